// Round 7
// baseline (235.856 us; speedup 1.0000x reference)
//
#include <hip/hip_runtime.h>
#include <math.h>

// Denoiser, fully fused:
//   K1: build bases via LDS cos-table (fwd DFT basis; OLA-folded inverse W)
//   K2: reflect-pad + bf16-cast audio (short8 vectorized) + zero ft row 0
//   K3: GEMM1 (STFT) + fused nonlin -> ft bf16   [XCD-swizzled, A-direct-reg,
//       B double-buffered 2-phase prefetch]
//   K4: GEMM2 (iSTFT+OLA folded, 2-group split-K) -> out [same schedule]
//
// Channel map (M=K=1024): c in [0,513) = re_c ; 512+k = im_k (k>=1).
// GEMM2: out[fo*256+h-512] = sum_{d,c} W[h][d*1024+c] * ft[fo-d+1][c],
//        fo in [2,4097]; ft row f' = frame f+1, rows 0 and >=4098 are zero.
//
// Workspace:
//   fwd  @ 0          : 1024*1024*2 = 2 MB
//   invW @ 2,097,152  : 256*4096*2  = 2 MB
//   aud  @ 4,194,304  : 4*1,082,368*2 = 8.66 MB
//   ft   @ 12,853,248 : 4*4232*1024*2 = 34.67 MB   (ends 47.5 MB)

#define NFFT 1024
#define HOP  256
#define CUT  513
#define NB   4
#define LAUD 1048576
#define NFR  4097
#define NFRP 4224
#define FTROWS 4232
#define ABLEN 1082368

typedef __attribute__((ext_vector_type(4))) float f32x4;
typedef __attribute__((ext_vector_type(8))) short bf16x8;

#define AS1 __attribute__((address_space(1)))
#define AS3 __attribute__((address_space(3)))

__device__ __forceinline__ unsigned short f2bf(float x) {
    unsigned u = __float_as_uint(x);
    u += 0x7FFF + ((u >> 16) & 1);   // RNE
    return (unsigned short)(u >> 16);
}

// ---- K1: bases from a 1024-entry cos table ---------------------------------
__global__ __launch_bounds__(256) void build_bases_k(
    ushort* __restrict__ fwd, ushort* __restrict__ invW) {
    __shared__ float ctab[1024];
    const int tid = threadIdx.x, bx = blockIdx.x;   // grid 256
    const float CST = 6.135923151542565e-3f;        // 2*pi/1024
    #pragma unroll
    for (int i = 0; i < 4; ++i) ctab[(i << 8) + tid] = cosf(CST * (float)((i << 8) + tid));
    __syncthreads();
    // fwd[c][n], n-fastest (coalesced)
    #pragma unroll
    for (int r = 0; r < 4; ++r) {
        int c = (bx << 2) + r;
        int k = (c < CUT) ? c : (c - 512);
        #pragma unroll
        for (int ch = 0; ch < 4; ++ch) {
            int n = (ch << 8) + tid;
            int m = (k * n) & 1023;
            float base = (c < CUT) ? ctab[m] : -ctab[(m + 768) & 1023]; // sin t = cos(t-pi/2)
            float win = 0.5f - 0.5f * ctab[n];
            fwd[(c << 10) + n] = f2bf(base * win);
        }
    }
    // invW[(n&255)<<12 | (n>>8)<<10 | c], c-fastest (coalesced)
    #pragma unroll
    for (int r = 0; r < 4; ++r) {
        int n = (bx << 2) + r;
        float win = 0.5f - 0.5f * ctab[n];
        long obase = ((long)(n & 255) << 12) + ((long)(n >> 8) << 10);
        #pragma unroll
        for (int ch = 0; ch < 4; ++ch) {
            int c = (ch << 8) + tid;
            int k = (c < CUT) ? c : (c - 512);
            int m = (k * n) & 1023;
            float base = (c < CUT) ? ctab[m] : -ctab[(m + 768) & 1023];
            float d = (c == 0 || c == 512) ? (1.0f / 1024.0f) : (2.0f / 1024.0f);
            invW[obase + c] = f2bf(0.25f * base * d * win);
        }
    }
}

// ---- K2: pad+cast audio (vectorized) + zero ft row 0 ------------------------
__global__ void cvt_audio_k(const float* __restrict__ audio,
                            ushort* __restrict__ aud, ushort* __restrict__ ft) {
    const int NV = ABLEN / 8;                      // 135296
    int idx = blockIdx.x * blockDim.x + threadIdx.x;
    if (idx < NB * NV) {
        int b = idx / NV;
        int t8 = (idx - b * NV) << 3;
        const float* ap = audio + (long)b * LAUD;
        ushort o[8];
        int j0 = t8 - 512;
        if (j0 >= 0 && j0 + 7 < LAUD) {            // interior: straight copy
            f32x4 v0 = *(const f32x4*)(ap + j0);
            f32x4 v1 = *(const f32x4*)(ap + j0 + 4);
            #pragma unroll
            for (int q = 0; q < 4; ++q) { o[q] = f2bf(v0[q]); o[4 + q] = f2bf(v1[q]); }
        } else {
            #pragma unroll
            for (int q = 0; q < 8; ++q) {
                int t = t8 + q;
                float v = 0.f;
                if (t < LAUD + 1024) {
                    int j = t - 512;
                    if (j < 0) j = -j;
                    if (j >= LAUD) j = 2 * LAUD - 2 - j;
                    v = ap[j];
                }
                o[q] = f2bf(v);
            }
        }
        *(ushort4*)(aud + (long)b * ABLEN + t8)     = *(ushort4*)&o[0];
        *(ushort4*)(aud + (long)b * ABLEN + t8 + 4) = *(ushort4*)&o[4];
    } else if (idx < NB * NV + 512) {              // zero ft row 0 (frame -1)
        int e = idx - NB * NV;
        int b = e >> 7, c8 = (e & 127) << 3;
        ushort z[8] = {};
        *(ushort4*)(ft + (long)b * FTROWS * 1024 + c8)     = *(ushort4*)&z[0];
        *(ushort4*)(ft + (long)b * FTROWS * 1024 + c8 + 4) = *(ushort4*)&z[4];
    }
}

// ---- K3: GEMM1 STFT + fused nonlin -----------------------------------------
// A (basis) direct global->reg; B (audio frames) LDS double-buffered,
// staged for step t+1 before computing step t; ONE barrier per K-step.
__global__ __launch_bounds__(256) void gemm_fwd_k(
    const ushort* __restrict__ fwd, const ushort* __restrict__ aud,
    const float* __restrict__ bias, ushort* __restrict__ ft) {
    __shared__ char smem[32768];  // B: 2 x 16KB
    const int tid = threadIdx.x;
    const int wid = tid >> 6, lane = tid & 63;
    const int lh = lane & 15, lg = lane >> 4;
    const int wm = wid >> 1, wn = wid & 1;
    int w = (blockIdx.x & 7) * 132 + (blockIdx.x >> 3);   // bijective XCD swizzle
    const int f0 = (w % 33) << 7;
    const int c0 = ((w / 33) & 7) << 6;
    const int b  = w / 264;
    const ushort* ab = aud + (long)b * ABLEN;

    const ushort* apt[4];   // per-lane A fragment base pointers
    #pragma unroll
    for (int i = 0; i < 4; ++i) {
        int r = (wm << 6) + (i << 4) + lh;
        int grow = ((r >> 4) & 1) * 512 + c0 + ((r >> 5) << 4) + (r & 15);
        apt[i] = fwd + (grow << 10) + (lg << 3);
    }

    f32x4 acc[4][4] = {};
    // prologue: stage B(k0=0) into buf0
    #pragma unroll
    for (int i = 0; i < 4; ++i) {
        int ci = (i << 8) + tid;
        int row = ci >> 3;
        int ks = ((ci & 7) ^ (row & 7)) << 3;
        __builtin_amdgcn_global_load_lds(
            (const AS1 unsigned int*)(ab + (f0 + row) * HOP + ks),
            (AS3 unsigned int*)(smem + (i << 12) + (wid << 10)), 16, 0, 0);
    }
    __syncthreads();

    for (int k0 = 0; k0 < 1024; k0 += 64) {
        const int cur = (k0 >> 6) & 1;
        if (k0 < 960) {  // stage next K-step into the other buffer
            #pragma unroll
            for (int i = 0; i < 4; ++i) {
                int ci = (i << 8) + tid;
                int row = ci >> 3;
                int ks = k0 + 64 + (((ci & 7) ^ (row & 7)) << 3);
                __builtin_amdgcn_global_load_lds(
                    (const AS1 unsigned int*)(ab + (f0 + row) * HOP + ks),
                    (AS3 unsigned int*)(smem + ((cur ^ 1) << 14) + (i << 12) + (wid << 10)),
                    16, 0, 0);
            }
        }
        bf16x8 avA[4], avB[4];
        #pragma unroll
        for (int i = 0; i < 4; ++i) {   // A frags for both half-steps, issued early
            avA[i] = *(const bf16x8*)(apt[i] + k0);
            avB[i] = *(const bf16x8*)(apt[i] + k0 + 32);
        }
        #pragma unroll
        for (int s = 0; s < 2; ++s) {
            bf16x8 bv[4];
            #pragma unroll
            for (int i = 0; i < 4; ++i) {
                int q = (wn << 6) + (i << 4) + lh;
                bv[i] = *(const bf16x8*)(smem + (cur << 14) + (q << 7) + ((((s << 2) + lg) ^ (q & 7)) << 4));
            }
            #pragma unroll
            for (int i = 0; i < 4; ++i)
                #pragma unroll
                for (int j = 0; j < 4; ++j)
                    acc[i][j] = __builtin_amdgcn_mfma_f32_16x16x32_bf16(
                        s ? avB[i] : avA[i], bv[j], acc[i][j], 0, 0, 0);
        }
        __syncthreads();
    }
    // fused nonlin epilogue: pairs (acc[2p], acc[2p+1]) = (re, im) rows.
    ushort* ftb = ft + (long)b * FTROWS * 1024 + 1024;  // f' = f+1
    float b512 = bias[512] * 0.1f;
    #pragma unroll
    for (int p = 0; p < 2; ++p) {
        int kbase = c0 + ((wm * 2 + p) << 4) + (lg << 2);
        float bs[4];
        #pragma unroll
        for (int q = 0; q < 4; ++q) bs[q] = bias[kbase + q] * 0.1f;
        #pragma unroll
        for (int j = 0; j < 4; ++j) {
            int f = f0 + (wn << 6) + (j << 4) + lh;
            bool valid = (f < NFR);   // frames >= NFR must be stored as ZERO
            ushort4 ore, oim;
            #pragma unroll
            for (int q = 0; q < 4; ++q) {
                float re = acc[2 * p][j][q], im = acc[2 * p + 1][j][q];
                float sre, sim;
                if (kbase + q == 0) {  // re_0 / re_512: independent lone channels
                    float mre = fabsf(re), mim = fabsf(im);
                    sre = mre > 0.f ? fmaxf(mre - bs[0], 0.f) / mre : 0.f;
                    sim = mim > 0.f ? fmaxf(mim - b512, 0.f) / mim : 0.f;
                } else {
                    float mag = sqrtf(re * re + im * im);
                    float s = mag > 0.f ? fmaxf(mag - bs[q], 0.f) / mag : 0.f;
                    sre = s; sim = s;
                }
                ((unsigned short*)&ore)[q] = f2bf(valid ? re * sre : 0.f);
                ((unsigned short*)&oim)[q] = f2bf(valid ? im * sim : 0.f);
            }
            *(ushort4*)(ftb + ((long)f << 10) + kbase) = ore;
            *(ushort4*)(ftb + ((long)f << 10) + 512 + kbase) = oim;
        }
    }
}

// ---- K4: GEMM2 iSTFT+OLA (M=256, K=4096, N=fo), 2-group split-K -------------
// A (invW) direct global->reg; B (ft rows) LDS double-buffered per group.
__global__ __launch_bounds__(512) void gemm_ola_k(
    const ushort* __restrict__ invW, const ushort* __restrict__ ft,
    float* __restrict__ out) {
    __shared__ char smem[32768];  // staging: g*16K + buf*8K; red (32KB) aliases
    const int tid = threadIdx.x;
    const int wid = tid >> 6, lane = tid & 63;
    const int lh = lane & 15, lg = lane >> 4;
    const int g = wid >> 2;
    const int wid2 = wid & 3;
    const int wm = wid2 >> 1, wn = wid2 & 1;
    const int tg = tid & 255;
    int w = (blockIdx.x & 7) * 64 + (blockIdx.x >> 3);    // bijective XCD swizzle
    const int h0  = (w & 1) << 7;
    const int fo0 = 2 + (((w >> 1) & 63) << 6);
    const int b   = w >> 7;
    const ushort* ftb = ft + (long)b * FTROWS * 1024;
    char* sg = smem + g * 16384;

    const ushort* apt[4];
    #pragma unroll
    for (int i = 0; i < 4; ++i) {
        int r = (wm << 6) + (i << 4) + lh;
        apt[i] = invW + ((long)(h0 + r) << 12) + (g << 11) + (lg << 3);
    }

    f32x4 acc[4][2] = {};
    // prologue: stage B(k0=0) into buf0
    {
        int kk = g << 11;
        int d = kk >> 10, cb = kk & 1023;
        #pragma unroll
        for (int i = 0; i < 2; ++i) {
            int ci = (i << 8) + tg;
            int row = ci >> 3;
            int swz = (((ci & 7) ^ (row & 7)) << 3);
            int frow = fo0 + row - d + 1;
            __builtin_amdgcn_global_load_lds(
                (const AS1 unsigned int*)(ftb + ((long)frow << 10) + cb + swz),
                (AS3 unsigned int*)(sg + (i << 12) + (wid2 << 10)), 16, 0, 0);
        }
    }
    __syncthreads();

    for (int k0 = 0; k0 < 2048; k0 += 64) {
        const int cur = (k0 >> 6) & 1;
        if (k0 < 1984) {   // stage next K-step
            int kk = (g << 11) + k0 + 64;
            int d = kk >> 10, cb = kk & 1023;
            #pragma unroll
            for (int i = 0; i < 2; ++i) {
                int ci = (i << 8) + tg;
                int row = ci >> 3;
                int swz = (((ci & 7) ^ (row & 7)) << 3);
                int frow = fo0 + row - d + 1;
                __builtin_amdgcn_global_load_lds(
                    (const AS1 unsigned int*)(ftb + ((long)frow << 10) + cb + swz),
                    (AS3 unsigned int*)(sg + ((cur ^ 1) << 13) + (i << 12) + (wid2 << 10)),
                    16, 0, 0);
            }
        }
        bf16x8 avA[4], avB[4];
        #pragma unroll
        for (int i = 0; i < 4; ++i) {
            avA[i] = *(const bf16x8*)(apt[i] + k0);
            avB[i] = *(const bf16x8*)(apt[i] + k0 + 32);
        }
        #pragma unroll
        for (int s = 0; s < 2; ++s) {
            bf16x8 bv[2];
            #pragma unroll
            for (int j = 0; j < 2; ++j) {
                int rq = (wn << 5) + (j << 4) + lh;
                bv[j] = *(const bf16x8*)(sg + (cur << 13) + (rq << 7) + ((((s << 2) + lg) ^ (rq & 7)) << 4));
            }
            #pragma unroll
            for (int i = 0; i < 4; ++i)
                #pragma unroll
                for (int j = 0; j < 2; ++j)
                    acc[i][j] = __builtin_amdgcn_mfma_f32_16x16x32_bf16(
                        s ? avB[i] : avA[i], bv[j], acc[i][j], 0, 0, 0);
        }
        __syncthreads();
    }
    // combine group 1 into group 0 through LDS (32KB f32 [h_local][fo_local])
    float* red = (float*)smem;
    if (g == 1) {
        #pragma unroll
        for (int i = 0; i < 4; ++i)
            #pragma unroll
            for (int j = 0; j < 2; ++j) {
                int hl = (wm << 6) + (i << 4) + (lg << 2);
                int fl = (wn << 5) + (j << 4) + lh;
                #pragma unroll
                for (int q = 0; q < 4; ++q)
                    red[(hl + q) * 64 + fl] = acc[i][j][q];
            }
    }
    __syncthreads();
    if (g == 1) return;
    float* ob = out + (long)b * LAUD;
    const float CST = 6.135923151542565e-3f;
    #pragma unroll
    for (int i = 0; i < 4; ++i) {
        int hbase = h0 + (wm << 6) + (i << 4) + (lg << 2);
        int hl = (wm << 6) + (i << 4) + (lg << 2);
        #pragma unroll
        for (int j = 0; j < 2; ++j) {
            int fo = fo0 + (wn << 5) + (j << 4) + lh;
            int fl = (wn << 5) + (j << 4) + lh;
            f32x4 v = acc[i][j];
            #pragma unroll
            for (int q = 0; q < 4; ++q) v[q] += red[(hl + q) * 64 + fl];
            if (fo == 2 || fo == 4097) {       // partial window-sum at the edges
                #pragma unroll
                for (int q = 0; q < 4; ++q) {
                    int n = (fo == 2) ? (hbase + q + 768) : (hbase + q);
                    float w2 = 0.5f - 0.5f * cosf(CST * (float)n);
                    v[q] = v[q] * (4.0f / (1.5f - w2 * w2));
                }
            } else {
                v *= (8.0f / 3.0f);            // interior: ws == 1.5 exactly
            }
            *(f32x4*)(ob + (((long)(fo - 2)) << 8) + hbase) = v;
        }
    }
}

extern "C" void kernel_launch(void* const* d_in, const int* in_sizes, int n_in,
                              void* d_out, int out_size, void* d_ws, size_t ws_size,
                              hipStream_t stream) {
    const float* audio = (const float*)d_in[0];
    const float* bias  = (const float*)d_in[1];
    float* out = (float*)d_out;
    char* wsb = (char*)d_ws;

    ushort* fwd  = (ushort*)(wsb);
    ushort* invW = (ushort*)(wsb + 2097152);
    ushort* aud  = (ushort*)(wsb + 4194304);
    ushort* ft   = (ushort*)(wsb + 12853248);

    build_bases_k<<<256, 256, 0, stream>>>(fwd, invW);

    int cvt_total = NB * (ABLEN / 8) + 512;
    cvt_audio_k<<<(cvt_total + 255) / 256, 256, 0, stream>>>(audio, aud, ft);

    gemm_fwd_k<<<1056, 256, 0, stream>>>(fwd, aud, bias, ft);

    gemm_ola_k<<<512, 512, 0, stream>>>(invW, ft, out);
}

// Round 8
// 108.342 us; speedup vs baseline: 2.1770x; 2.1770x over previous
//
#include <hip/hip_runtime.h>
#include <math.h>

// Denoiser, fully fused:
//   K1: build bases via LDS cos-table (fwd DFT basis; OLA-folded inverse W)
//   K2: reflect-pad + bf16-cast audio (vectorized) + zero ft row 0
//   K3: GEMM1 (STFT) + fused nonlin -> ft bf16   [XCD-swizzled, LDS-staged]
//   K4: GEMM2 (iSTFT+OLA folded, 2-group split-K) -> out [XCD-swizzled]
//
// Channel map (M=K=1024): c in [0,513) = re_c ; 512+k = im_k (k>=1).
// GEMM2: out[fo*256+h-512] = sum_{d,c} W[h][d*1024+c] * ft[fo-d+1][c],
//        fo in [2,4097]; ft row f' = frame f+1, rows 0 and >=4098 are zero.
//
// Workspace:
//   fwd  @ 0          : 1024*1024*2 = 2 MB
//   invW @ 2,097,152  : 256*4096*2  = 2 MB
//   aud  @ 4,194,304  : 4*1,082,368*2 = 8.66 MB
//   ft   @ 12,853,248 : 4*4232*1024*2 = 34.67 MB   (ends 47.5 MB)

#define NFFT 1024
#define HOP  256
#define CUT  513
#define NB   4
#define LAUD 1048576
#define NFR  4097
#define NFRP 4224
#define FTROWS 4232
#define ABLEN 1082368

typedef __attribute__((ext_vector_type(4))) float f32x4;
typedef __attribute__((ext_vector_type(8))) short bf16x8;

#define AS1 __attribute__((address_space(1)))
#define AS3 __attribute__((address_space(3)))

__device__ __forceinline__ unsigned short f2bf(float x) {
    unsigned u = __float_as_uint(x);
    u += 0x7FFF + ((u >> 16) & 1);   // RNE
    return (unsigned short)(u >> 16);
}

// ---- K1: bases from a 1024-entry cos table ---------------------------------
__global__ __launch_bounds__(256) void build_bases_k(
    ushort* __restrict__ fwd, ushort* __restrict__ invW) {
    __shared__ float ctab[1024];
    const int tid = threadIdx.x, bx = blockIdx.x;   // grid 256
    const float CST = 6.135923151542565e-3f;        // 2*pi/1024
    #pragma unroll
    for (int i = 0; i < 4; ++i) ctab[(i << 8) + tid] = cosf(CST * (float)((i << 8) + tid));
    __syncthreads();
    // fwd[c][n], n-fastest (coalesced)
    #pragma unroll
    for (int r = 0; r < 4; ++r) {
        int c = (bx << 2) + r;
        int k = (c < CUT) ? c : (c - 512);
        #pragma unroll
        for (int ch = 0; ch < 4; ++ch) {
            int n = (ch << 8) + tid;
            int m = (k * n) & 1023;
            float base = (c < CUT) ? ctab[m] : -ctab[(m + 768) & 1023]; // sin t = cos(t-pi/2)
            float win = 0.5f - 0.5f * ctab[n];
            fwd[(c << 10) + n] = f2bf(base * win);
        }
    }
    // invW[(n&255)<<12 | (n>>8)<<10 | c], c-fastest (coalesced)
    #pragma unroll
    for (int r = 0; r < 4; ++r) {
        int n = (bx << 2) + r;
        float win = 0.5f - 0.5f * ctab[n];
        long obase = ((long)(n & 255) << 12) + ((long)(n >> 8) << 10);
        #pragma unroll
        for (int ch = 0; ch < 4; ++ch) {
            int c = (ch << 8) + tid;
            int k = (c < CUT) ? c : (c - 512);
            int m = (k * n) & 1023;
            float base = (c < CUT) ? ctab[m] : -ctab[(m + 768) & 1023];
            float d = (c == 0 || c == 512) ? (1.0f / 1024.0f) : (2.0f / 1024.0f);
            invW[obase + c] = f2bf(0.25f * base * d * win);
        }
    }
}

// ---- K2: pad+cast audio (vectorized) + zero ft row 0 ------------------------
__global__ void cvt_audio_k(const float* __restrict__ audio,
                            ushort* __restrict__ aud, ushort* __restrict__ ft) {
    const int NV = ABLEN / 8;                      // 135296
    int idx = blockIdx.x * blockDim.x + threadIdx.x;
    if (idx < NB * NV) {
        int b = idx / NV;
        int t8 = (idx - b * NV) << 3;
        const float* ap = audio + (long)b * LAUD;
        ushort o[8];
        int j0 = t8 - 512;
        if (j0 >= 0 && j0 + 7 < LAUD) {            // interior: straight copy
            f32x4 v0 = *(const f32x4*)(ap + j0);
            f32x4 v1 = *(const f32x4*)(ap + j0 + 4);
            #pragma unroll
            for (int q = 0; q < 4; ++q) { o[q] = f2bf(v0[q]); o[4 + q] = f2bf(v1[q]); }
        } else {
            #pragma unroll
            for (int q = 0; q < 8; ++q) {
                int t = t8 + q;
                float v = 0.f;
                if (t < LAUD + 1024) {
                    int j = t - 512;
                    if (j < 0) j = -j;
                    if (j >= LAUD) j = 2 * LAUD - 2 - j;
                    v = ap[j];
                }
                o[q] = f2bf(v);
            }
        }
        *(ushort4*)(aud + (long)b * ABLEN + t8)     = *(ushort4*)&o[0];
        *(ushort4*)(aud + (long)b * ABLEN + t8 + 4) = *(ushort4*)&o[4];
    } else if (idx < NB * NV + 512) {              // zero ft row 0 (frame -1)
        int e = idx - NB * NV;
        int b = e >> 7, c8 = (e & 127) << 3;
        ushort z[8] = {};
        *(ushort4*)(ft + (long)b * FTROWS * 1024 + c8)     = *(ushort4*)&z[0];
        *(ushort4*)(ft + (long)b * FTROWS * 1024 + c8 + 4) = *(ushort4*)&z[4];
    }
}

// ---- K3: GEMM1 STFT + fused nonlin (proven R5 structure) --------------------
// A-tile rows interleaved: local row r -> group g=r>>4 (even: re, odd: im).
__global__ __launch_bounds__(256) void gemm_fwd_k(
    const ushort* __restrict__ fwd, const ushort* __restrict__ aud,
    const float* __restrict__ bias, ushort* __restrict__ ft) {
    __shared__ char smem[32768];  // A 16K | B 16K
    const int tid = threadIdx.x;
    const int wid = tid >> 6, lane = tid & 63;
    const int lh = lane & 15, lg = lane >> 4;
    const int wm = wid >> 1, wn = wid & 1;
    // bijective XCD swizzle: 1056 = 8 * 132
    int w = (blockIdx.x & 7) * 132 + (blockIdx.x >> 3);
    const int f0 = (w % 33) << 7;
    const int c0 = ((w / 33) & 7) << 6;
    const int b  = w / 264;
    const ushort* ab = aud + (long)b * ABLEN;
    f32x4 acc[4][4] = {};

    for (int k0 = 0; k0 < 1024; k0 += 64) {
        if (k0) __syncthreads();
        #pragma unroll
        for (int i = 0; i < 4; ++i) {
            int ci = (i << 8) + tid;
            int row = ci >> 3;
            int ks = k0 + (((ci & 7) ^ (row & 7)) << 3);  // pre-swizzled source
            int grow = ((row >> 4) & 1) * 512 + c0 + ((row >> 5) << 4) + (row & 15);
            __builtin_amdgcn_global_load_lds(
                (const AS1 unsigned int*)(fwd + (grow << 10) + ks),
                (AS3 unsigned int*)(smem + (i << 12) + (wid << 10)), 16, 0, 0);
            __builtin_amdgcn_global_load_lds(
                (const AS1 unsigned int*)(ab + (f0 + row) * HOP + ks),
                (AS3 unsigned int*)(smem + 16384 + (i << 12) + (wid << 10)), 16, 0, 0);
        }
        __syncthreads();
        #pragma unroll
        for (int s = 0; s < 2; ++s) {
            bf16x8 av[4], bv[4];
            #pragma unroll
            for (int i = 0; i < 4; ++i) {
                int r = (wm << 6) + (i << 4) + lh;
                av[i] = *(const bf16x8*)(smem + (r << 7) + ((((s << 2) + lg) ^ (r & 7)) << 4));
                int q = (wn << 6) + (i << 4) + lh;
                bv[i] = *(const bf16x8*)(smem + 16384 + (q << 7) + ((((s << 2) + lg) ^ (q & 7)) << 4));
            }
            #pragma unroll
            for (int i = 0; i < 4; ++i)
                #pragma unroll
                for (int j = 0; j < 4; ++j)
                    acc[i][j] = __builtin_amdgcn_mfma_f32_16x16x32_bf16(av[i], bv[j], acc[i][j], 0, 0, 0);
        }
    }
    // fused nonlin epilogue: pairs (acc[2p], acc[2p+1]) = (re, im) rows.
    ushort* ftb = ft + (long)b * FTROWS * 1024 + 1024;  // f' = f+1
    float b512 = bias[512] * 0.1f;
    #pragma unroll
    for (int p = 0; p < 2; ++p) {
        int kbase = c0 + ((wm * 2 + p) << 4) + (lg << 2);
        float bs[4];
        #pragma unroll
        for (int q = 0; q < 4; ++q) bs[q] = bias[kbase + q] * 0.1f;
        #pragma unroll
        for (int j = 0; j < 4; ++j) {
            int f = f0 + (wn << 6) + (j << 4) + lh;
            bool valid = (f < NFR);   // frames >= NFR must be stored as ZERO
            ushort4 ore, oim;
            #pragma unroll
            for (int q = 0; q < 4; ++q) {
                float re = acc[2 * p][j][q], im = acc[2 * p + 1][j][q];
                float sre, sim;
                if (kbase + q == 0) {  // re_0 / re_512: independent lone channels
                    float mre = fabsf(re), mim = fabsf(im);
                    sre = mre > 0.f ? fmaxf(mre - bs[0], 0.f) / mre : 0.f;
                    sim = mim > 0.f ? fmaxf(mim - b512, 0.f) / mim : 0.f;
                } else {
                    float mag = sqrtf(re * re + im * im);
                    float s = mag > 0.f ? fmaxf(mag - bs[q], 0.f) / mag : 0.f;
                    sre = s; sim = s;
                }
                ((unsigned short*)&ore)[q] = f2bf(valid ? re * sre : 0.f);
                ((unsigned short*)&oim)[q] = f2bf(valid ? im * sim : 0.f);
            }
            *(ushort4*)(ftb + ((long)f << 10) + kbase) = ore;
            *(ushort4*)(ftb + ((long)f << 10) + 512 + kbase) = oim;
        }
    }
}

// ---- K4: GEMM2 iSTFT+OLA (proven R5 split-K structure) ----------------------
// 512 threads, 8 waves = 2 K-groups of 4 waves (d{0,1} | d{2,3}); combined
// through LDS at the end.
__global__ __launch_bounds__(512) void gemm_ola_k(
    const ushort* __restrict__ invW, const ushort* __restrict__ ft,
    float* __restrict__ out) {
    __shared__ char smem[49152];  // group0: A 16K | B 8K ; group1 at +24576
    const int tid = threadIdx.x;
    const int wid = tid >> 6, lane = tid & 63;
    const int lh = lane & 15, lg = lane >> 4;
    const int g = wid >> 2;           // K-group
    const int wid2 = wid & 3;
    const int wm = wid2 >> 1, wn = wid2 & 1;
    const int tg = tid & 255;         // tid within group
    // bijective XCD swizzle: 512 = 8 * 64; work order: h fastest, then fo, b
    int w = (blockIdx.x & 7) * 64 + (blockIdx.x >> 3);
    const int h0  = (w & 1) << 7;
    const int fo0 = 2 + (((w >> 1) & 63) << 6);
    const int b   = w >> 7;
    const ushort* ftb = ft + (long)b * FTROWS * 1024;
    char* sm = smem + g * 24576;
    f32x4 acc[4][2] = {};

    for (int k0 = 0; k0 < 2048; k0 += 64) {
        if (k0) __syncthreads();
        int kk = (g << 11) + k0;
        int d  = kk >> 10;
        int cb = kk & 1023;
        #pragma unroll
        for (int i = 0; i < 4; ++i) {  // A: W rows h0..h0+127
            int ci = (i << 8) + tg;
            int row = ci >> 3;
            int swz = (((ci & 7) ^ (row & 7)) << 3);
            __builtin_amdgcn_global_load_lds(
                (const AS1 unsigned int*)(invW + ((h0 + row) << 12) + kk + swz),
                (AS3 unsigned int*)(sm + (i << 12) + (wid2 << 10)), 16, 0, 0);
        }
        #pragma unroll
        for (int i = 0; i < 2; ++i) {  // B: rec rows fo0-d+1 .. +63
            int ci = (i << 8) + tg;
            int row = ci >> 3;
            int swz = (((ci & 7) ^ (row & 7)) << 3);
            int frow = fo0 + row - d + 1;
            __builtin_amdgcn_global_load_lds(
                (const AS1 unsigned int*)(ftb + ((long)frow << 10) + cb + swz),
                (AS3 unsigned int*)(sm + 16384 + (i << 12) + (wid2 << 10)), 16, 0, 0);
        }
        __syncthreads();
        #pragma unroll
        for (int s = 0; s < 2; ++s) {
            bf16x8 av[4], bv[2];
            #pragma unroll
            for (int i = 0; i < 4; ++i) {
                int r = (wm << 6) + (i << 4) + lh;
                av[i] = *(const bf16x8*)(sm + (r << 7) + ((((s << 2) + lg) ^ (r & 7)) << 4));
            }
            #pragma unroll
            for (int j = 0; j < 2; ++j) {
                int rq = (wn << 5) + (j << 4) + lh;
                bv[j] = *(const bf16x8*)(sm + 16384 + (rq << 7) + ((((s << 2) + lg) ^ (rq & 7)) << 4));
            }
            #pragma unroll
            for (int i = 0; i < 4; ++i)
                #pragma unroll
                for (int j = 0; j < 2; ++j)
                    acc[i][j] = __builtin_amdgcn_mfma_f32_16x16x32_bf16(av[i], bv[j], acc[i][j], 0, 0, 0);
        }
    }
    // ---- combine group 1 into group 0 through LDS (32KB f32, [h][fo]) ------
    __syncthreads();
    float* red = (float*)smem;
    if (g == 1) {
        #pragma unroll
        for (int i = 0; i < 4; ++i)
            #pragma unroll
            for (int j = 0; j < 2; ++j) {
                int hl = (wm << 6) + (i << 4) + (lg << 2);
                int fl = (wn << 5) + (j << 4) + lh;
                #pragma unroll
                for (int q = 0; q < 4; ++q)
                    red[(hl + q) * 64 + fl] = acc[i][j][q];
            }
    }
    __syncthreads();
    if (g == 1) return;
    float* ob = out + (long)b * LAUD;
    const float CST = 6.135923151542565e-3f;
    #pragma unroll
    for (int i = 0; i < 4; ++i) {
        int hbase = h0 + (wm << 6) + (i << 4) + (lg << 2);
        int hl = (wm << 6) + (i << 4) + (lg << 2);
        #pragma unroll
        for (int j = 0; j < 2; ++j) {
            int fo = fo0 + (wn << 5) + (j << 4) + lh;
            int fl = (wn << 5) + (j << 4) + lh;
            f32x4 v = acc[i][j];
            #pragma unroll
            for (int q = 0; q < 4; ++q) v[q] += red[(hl + q) * 64 + fl];
            if (fo == 2 || fo == 4097) {       // partial window-sum at the edges
                #pragma unroll
                for (int q = 0; q < 4; ++q) {
                    int n = (fo == 2) ? (hbase + q + 768) : (hbase + q);
                    float w2 = 0.5f - 0.5f * cosf(CST * (float)n);
                    v[q] = v[q] * (4.0f / (1.5f - w2 * w2));
                }
            } else {
                v *= (8.0f / 3.0f);            // interior: ws == 1.5 exactly
            }
            *(f32x4*)(ob + (((long)(fo - 2)) << 8) + hbase) = v;
        }
    }
}

extern "C" void kernel_launch(void* const* d_in, const int* in_sizes, int n_in,
                              void* d_out, int out_size, void* d_ws, size_t ws_size,
                              hipStream_t stream) {
    const float* audio = (const float*)d_in[0];
    const float* bias  = (const float*)d_in[1];
    float* out = (float*)d_out;
    char* wsb = (char*)d_ws;

    ushort* fwd  = (ushort*)(wsb);
    ushort* invW = (ushort*)(wsb + 2097152);
    ushort* aud  = (ushort*)(wsb + 4194304);
    ushort* ft   = (ushort*)(wsb + 12853248);

    build_bases_k<<<256, 256, 0, stream>>>(fwd, invW);

    int cvt_total = NB * (ABLEN / 8) + 512;
    cvt_audio_k<<<(cvt_total + 255) / 256, 256, 0, stream>>>(audio, aud, ft);

    gemm_fwd_k<<<1056, 256, 0, stream>>>(fwd, aud, bias, ft);

    gemm_ola_k<<<512, 512, 0, stream>>>(invW, ft, out);
}